// Round 8
// baseline (2213.276 us; speedup 1.0000x reference)
//
#include <hip/hip_runtime.h>
#include <math.h>

#define NEG_SLOPE 0.2f

// safe (CAS-based) float atomic add — correct on any memory type
static __device__ __forceinline__ void atomAdd(float* a, float v) {
    atomicAdd(a, v);
}

// Edge-layout probe (wave-uniform): int64 indices (< 2^31) have all-zero odd
// 32-bit words; int32 real edge data has ~U[0,N) odd words. FP prob ~1e-19.
static __device__ __forceinline__ bool edges_are_i64(const int* __restrict__ ei) {
    return (ei[1] | ei[3] | ei[5] | ei[7]) == 0;
}

static __device__ __forceinline__ void ldedge(const int* __restrict__ ei, int e, int E,
                                              bool i64, int& s, int& d) {
    if (i64) { s = ei[2 * e]; d = ei[2 * (E + e)]; }
    else     { s = ei[e];     d = ei[E + e]; }
}

// diagnostic marker: runs FIRST; overwritten by final_k iff pipeline completes
__global__ void marker_k(float* __restrict__ out) {
    out[0] = 6.7f; out[1] = 6.7f; out[2] = 6.7f;
}

__global__ void fill_f32(float* __restrict__ p, float v, int n) {
    int i = blockIdx.x * blockDim.x + threadIdx.x;
    if (i < n) p[i] = v;
}

// h1[N,128] = x[N,64] @ W1[64,128], fp32. 2 rows / 256-thread block.
__global__ __launch_bounds__(256) void gemm1_k(const float* __restrict__ x,
                                               const float* __restrict__ W,
                                               float* __restrict__ h, int N) {
    __shared__ float Ws[64 * 128];
    __shared__ float xs[2 * 64];
    int tid = threadIdx.x;
    for (int i = tid; i < 64 * 128; i += 256) Ws[i] = W[i];
    int row0 = blockIdx.x * 2;
    for (int i = tid; i < 2 * 64; i += 256) {
        int r = row0 + i / 64;
        xs[i] = (r < N) ? x[(size_t)r * 64 + (i % 64)] : 0.0f;
    }
    __syncthreads();
    int r = row0 + tid / 128;
    if (r >= N) return;
    int j = tid % 128;
    const float* xr = &xs[(tid / 128) * 64];
    float acc = 0.0f;
#pragma unroll
    for (int k = 0; k < 64; ++k) acc += xr[k] * Ws[k * 128 + j];
    h[(size_t)r * 128 + j] = acc;
}

// h2[N,32] = hact[N,128] @ W2[128,32]. 8 rows / block.
__global__ __launch_bounds__(256) void gemm2_k(const float* __restrict__ hact,
                                               const float* __restrict__ W,
                                               float* __restrict__ h2, int N) {
    __shared__ float Ws[128 * 32];
    __shared__ float xs[8 * 128];
    int tid = threadIdx.x;
    for (int i = tid; i < 128 * 32; i += 256) Ws[i] = W[i];
    int row0 = blockIdx.x * 8;
    for (int i = tid; i < 8 * 128; i += 256) {
        int r = row0 + i / 128;
        xs[i] = (r < N) ? hact[(size_t)r * 128 + (i % 128)] : 0.0f;
    }
    __syncthreads();
    int r = row0 + tid / 32;
    if (r >= N) return;
    int j = tid % 32;
    const float* xr = &xs[(tid / 32) * 128];
    float acc = 0.0f;
#pragma unroll 16
    for (int k = 0; k < 128; ++k) acc += xr[k] * Ws[k * 32 + j];
    h2[(size_t)r * 32 + j] = acc;
}

// a_src[n,h] = <h[n,h,:], att_src[h,:]> ; same for dst. One thread per (n,h).
template <int H>
__global__ void att_k(const float* __restrict__ h,
                      const float* __restrict__ aw_s,
                      const float* __restrict__ aw_d,
                      float* __restrict__ as_, float* __restrict__ ad_, int N) {
    int i = blockIdx.x * blockDim.x + threadIdx.x;
    if (i >= N * H) return;
    int hd = i % H;
    const float* hr = h + (size_t)(i / H) * (H * 32) + hd * 32;
    float s = 0.0f, d = 0.0f;
#pragma unroll
    for (int c = 0; c < 32; ++c) {
        float v = hr[c];
        s += v * aw_s[hd * 32 + c];
        d += v * aw_d[hd * 32 + c];
    }
    as_[i] = s;
    ad_[i] = d;
}

// den[d,h] += exp(leaky(a_src[s,h]+a_dst[d,h]))   (no max-shift: |e| is O(5))
template <int H>
__global__ void edge_den_k(const int* __restrict__ ei, const float* __restrict__ asrc,
                           const float* __restrict__ adst, float* __restrict__ den,
                           int E, int N) {
    int e = blockIdx.x * blockDim.x + threadIdx.x;
    if (e >= E + N) return;
    bool i64 = edges_are_i64(ei);
    int s, d;
    if (e < E) ldedge(ei, e, E, i64, s, d);
    else       { s = d = e - E; }
#pragma unroll
    for (int h = 0; h < H; ++h) {
        float v = asrc[s * H + h] + adst[d * H + h];
        v = v > 0.0f ? v : NEG_SLOPE * v;
        atomAdd(&den[d * H + h], __expf(v));
    }
}

// out[dst] += (exp(e)/den[dst]) * h[src]; (H*C)/4 lanes per edge, float4 gathers.
template <int H, int C>
__global__ __launch_bounds__(256) void edge_agg_k(const int* __restrict__ ei,
                                                  const float* __restrict__ asrc,
                                                  const float* __restrict__ adst,
                                                  const float* __restrict__ den,
                                                  const float* __restrict__ h,
                                                  float* __restrict__ out, int E, int N) {
    constexpr int CT = H * C;
    constexpr int L = CT / 4;
    int gt = blockIdx.x * 256 + threadIdx.x;
    int e = gt / L;
    int lane = gt % L;
    if (e >= E + N) return;
    bool i64 = edges_are_i64(ei);
    int s, d;
    if (e < E) ldedge(ei, e, E, i64, s, d);
    else       { s = d = e - E; }
    int hd = (lane * 4) / C;
    float v = asrc[s * H + hd] + adst[d * H + hd];
    v = v > 0.0f ? v : NEG_SLOPE * v;
    float alpha = __expf(v) / den[d * H + hd];
    const float4 hv = *(const float4*)(h + (size_t)s * CT + lane * 4);
    float* o = out + (size_t)d * CT + lane * 4;
    atomAdd(o + 0, hv.x * alpha);
    atomAdd(o + 1, hv.y * alpha);
    atomAdd(o + 2, hv.z * alpha);
    atomAdd(o + 3, hv.w * alpha);
}

__global__ void elu_bias_k(const float* __restrict__ a, const float* __restrict__ b,
                           float* __restrict__ o, int n) {
    int i = blockIdx.x * blockDim.x + threadIdx.x;
    if (i >= n) return;
    float v = a[i] + b[i & 127];
    o[i] = v > 0.0f ? v : expm1f(v);
}

// column sums of out2[N,32] -> atomicAdd into gsum[32]
__global__ __launch_bounds__(256) void colmean_k(const float* __restrict__ out2,
                                                 float* __restrict__ gsum, int N) {
    __shared__ float lds[256];
    int tid = threadIdx.x;
    int c = tid % 32;
    int rg = tid / 32;
    float acc = 0.0f;
    for (int r = blockIdx.x * 8 + rg; r < N; r += gridDim.x * 8)
        acc += out2[(size_t)r * 32 + c];
    lds[tid] = acc;
    __syncthreads();
    if (tid < 32) {
        float s = 0.0f;
#pragma unroll
        for (int g = 0; g < 8; ++g) s += lds[g * 32 + tid];
        atomAdd(&gsum[tid], s);
    }
}

// NOTE: output is FLOAT32 (reference returns fp32 softmax; harness: "else float*").
__global__ void final_k(const float* __restrict__ gsum, const float* __restrict__ b2w,
                        const float* __restrict__ linW, const float* __restrict__ linb,
                        float* __restrict__ out, int N) {
    if (threadIdx.x != 0 || blockIdx.x != 0) return;
    float g[32];
#pragma unroll
    for (int c = 0; c < 32; ++c) g[c] = gsum[c] / (float)N + b2w[c];
    float lo[3];
#pragma unroll
    for (int j = 0; j < 3; ++j) {
        float acc = linb[j];
#pragma unroll
        for (int c = 0; c < 32; ++c) acc += g[c] * linW[c * 3 + j];
        lo[j] = acc;
    }
    float mx = fmaxf(lo[0], fmaxf(lo[1], lo[2]));
    float ex[3], se = 0.0f;
#pragma unroll
    for (int j = 0; j < 3; ++j) { ex[j] = __expf(lo[j] - mx); se += ex[j]; }
#pragma unroll
    for (int j = 0; j < 3; ++j) out[j] = ex[j] / se;
}

extern "C" void kernel_launch(void* const* d_in, const int* in_sizes, int n_in,
                              void* d_out, int out_size, void* d_ws, size_t ws_size,
                              hipStream_t stream) {
    // Reference dtypes: float tensors jnp.float32 -> const float*; edge_index
    // integer -> int32 or int64 words (probed on device); OUTPUT fp32.
    const float* x    = (const float*)d_in[0];
    const float* W1   = (const float*)d_in[1];
    const float* as1w = (const float*)d_in[2];
    const float* ad1w = (const float*)d_in[3];
    const float* b1   = (const float*)d_in[4];
    const float* W2   = (const float*)d_in[5];
    const float* as2w = (const float*)d_in[6];
    const float* ad2w = (const float*)d_in[7];
    const float* b2w  = (const float*)d_in[8];
    const float* linW = (const float*)d_in[9];
    const float* linb = (const float*)d_in[10];
    const int*   ei   = (const int*)d_in[11];

    const int N  = in_sizes[0] / 64;       // 50000
    const int E  = in_sizes[11] / 2;       // 800000
    const int ET = E + N;

    float* ws = (float*)d_ws;
    // layer-1 buffers (all sizes multiples of 4 floats -> 16B alignment kept)
    float* h1    = ws;                       // N*128, reused as hact after ELU
    float* out1  = h1 + (size_t)N * 128;     // N*128
    float* asrc1 = out1 + (size_t)N * 128;   // N*4
    float* adst1 = asrc1 + (size_t)N * 4;    // N*4
    float* den1  = adst1 + (size_t)N * 4;    // N*4
    // layer-2 buffers alias out1 (dead after elu_bias_k); fills issued after elu.
    float* h2    = out1;                     // N*32
    float* out2  = h2 + (size_t)N * 32;      // N*32
    float* asrc2 = out2 + (size_t)N * 32;    // N
    float* adst2 = asrc2 + (size_t)N;        // N
    float* den2  = adst2 + (size_t)N;        // N
    float* gsum  = den2 + (size_t)N;         // 32

    auto cdiv = [](int a, int b) { return (a + b - 1) / b; };

    // diagnostic marker (6.7 everywhere unless final_k completes)
    marker_k<<<1, 1, 0, stream>>>((float*)d_out);

    // ---- layer 1 ----
    fill_f32<<<cdiv(N * 128, 256), 256, 0, stream>>>(out1, 0.0f, N * 128);
    fill_f32<<<cdiv(N * 4, 256), 256, 0, stream>>>(den1, 0.0f, N * 4);
    gemm1_k<<<cdiv(N, 2), 256, 0, stream>>>(x, W1, h1, N);
    att_k<4><<<cdiv(N * 4, 256), 256, 0, stream>>>(h1, as1w, ad1w, asrc1, adst1, N);
    edge_den_k<4><<<cdiv(ET, 256), 256, 0, stream>>>(ei, asrc1, adst1, den1, E, N);
    edge_agg_k<4, 32><<<cdiv(ET * 32, 256), 256, 0, stream>>>(ei, asrc1, adst1, den1, h1, out1, E, N);
    elu_bias_k<<<cdiv(N * 128, 256), 256, 0, stream>>>(out1, b1, h1, N * 128);  // hact -> h1

    // ---- layer 2 (fills after elu: out1 region is now dead) ----
    fill_f32<<<cdiv(N * 32, 256), 256, 0, stream>>>(out2, 0.0f, N * 32);
    fill_f32<<<cdiv(N, 256), 256, 0, stream>>>(den2, 0.0f, N);
    fill_f32<<<1, 32, 0, stream>>>(gsum, 0.0f, 32);
    gemm2_k<<<cdiv(N, 8), 256, 0, stream>>>(h1, W2, h2, N);
    att_k<1><<<cdiv(N, 256), 256, 0, stream>>>(h2, as2w, ad2w, asrc2, adst2, N);
    edge_den_k<1><<<cdiv(ET, 256), 256, 0, stream>>>(ei, asrc2, adst2, den2, E, N);
    edge_agg_k<1, 32><<<cdiv(ET * 8, 256), 256, 0, stream>>>(ei, asrc2, adst2, den2, h2, out2, E, N);

    // ---- readout ----
    colmean_k<<<256, 256, 0, stream>>>(out2, gsum, N);
    final_k<<<1, 64, 0, stream>>>(gsum, b2w, linW, linb, (float*)d_out, N);
}